// Round 1
// baseline (12382.088 us; speedup 1.0000x reference)
//
#include <hip/hip_runtime.h>
#include <math.h>

// Problem constants
#define BZ 32
#define FCH 160
#define HH 32
#define WW 32
#define NMIX 10
#define PCH 100

// ---------------------------------------------------------------------------
// Init conv for u: u = down_shift(ds_conv(xp, w(160,4,2,3), b))
// Row 0 is exactly zero (down_shift). Row i>=1: bias + sum taps x[i-2+kh, j-1+kw]
// Channel 3 of xp is constant 1.0 inside bounds (zero in pad region).
// ---------------------------------------------------------------------------
__global__ __launch_bounds__(256) void init_u_k(
    const float* __restrict__ smp, const float* __restrict__ w,
    const float* __restrict__ bias, float* __restrict__ u)
{
    int idx = blockIdx.x * 256 + threadIdx.x;
    if (idx >= BZ * FCH * 1024) return;
    int b = idx / (FCH * 1024);
    int rem = idx % (FCH * 1024);
    int o = rem >> 10;
    int ij = rem & 1023;
    int i = ij >> 5, j = ij & 31;
    if (i == 0) { u[idx] = 0.f; return; }
    float acc = bias[o];
    const float* wb = w + o * 4 * 6;  // [c:4][kh:2][kw:3]
    for (int kh = 0; kh < 2; ++kh) {
        int r = i - 2 + kh;
        if (r < 0) continue;
        for (int kw = 0; kw < 3; ++kw) {
            int cc = j - 1 + kw;
            if (cc < 0 || cc >= 32) continue;
            acc += wb[3 * 6 + kh * 3 + kw];  // ones channel
            for (int c = 0; c < 3; ++c) {
                float xv = smp[(((size_t)b * 3 + c) << 10) + (r << 5) + cc] * 2.f - 1.f;
                acc += wb[c * 6 + kh * 3 + kw] * xv;
            }
        }
    }
    u[idx] = acc;
}

// ---------------------------------------------------------------------------
// Init conv for ul: down_shift(ds_conv(xp, w_d(160,4,1,3))) +
//                   right_shift(dr_conv(xp, w_r(160,4,2,1)))
// ---------------------------------------------------------------------------
__global__ __launch_bounds__(256) void init_ul_k(
    const float* __restrict__ smp,
    const float* __restrict__ wd, const float* __restrict__ bd,
    const float* __restrict__ wr, const float* __restrict__ br,
    float* __restrict__ ul)
{
    int idx = blockIdx.x * 256 + threadIdx.x;
    if (idx >= BZ * FCH * 1024) return;
    int b = idx / (FCH * 1024);
    int rem = idx % (FCH * 1024);
    int o = rem >> 10;
    int ij = rem & 1023;
    int i = ij >> 5, j = ij & 31;
    float acc = 0.f;
    if (i >= 1) {  // down-shifted 1x3 conv: reads row i-1, cols j-1+kw
        acc += bd[o];
        const float* wb = wd + o * 4 * 3;
        int r = i - 1;
        for (int kw = 0; kw < 3; ++kw) {
            int cc = j - 1 + kw;
            if (cc < 0 || cc >= 32) continue;
            acc += wb[3 * 3 + kw];
            for (int c = 0; c < 3; ++c)
                acc += wb[c * 3 + kw] * (smp[(((size_t)b * 3 + c) << 10) + (r << 5) + cc] * 2.f - 1.f);
        }
    }
    if (j >= 1) {  // right-shifted 2x1 conv: reads rows i-1+kh, col j-1
        acc += br[o];
        const float* wb = wr + o * 4 * 2;
        int cc = j - 1;
        for (int kh = 0; kh < 2; ++kh) {
            int r = i - 1 + kh;
            if (r < 0) continue;
            acc += wb[3 * 2 + kh];
            for (int c = 0; c < 3; ++c)
                acc += wb[c * 2 + kh] * (smp[(((size_t)b * 3 + c) << 10) + (r << 5) + cc] * 2.f - 1.f);
        }
    }
    ul[idx] = acc;
}

// ---------------------------------------------------------------------------
// Main conv with fused concat_elu on the input.
// x: (B,160,H,W) fp32. Conv input channels = 320: [elu(x), elu(-x)].
// w: (Cout, 320, KH, KW). Pads: PT top, PL left (ds: 1,1 / dr: 1,1 / nin: 0,0).
// ACC: accumulate into existing y (y += conv + bias) vs y = conv + bias.
// Tile: 32 out-ch x 4 rows x 32 cols per block, 256 threads.
// ---------------------------------------------------------------------------
template <int KH, int KW, int PT, int PL, bool ACC>
__global__ __launch_bounds__(256) void conv_ce_k(
    const float* __restrict__ x, const float* __restrict__ w,
    const float* __restrict__ bias, float* __restrict__ y, int Cout)
{
    constexpr int RT = 4, OC = 32, CH = 8;
    constexpr int R = RT + KH - 1;
    constexpr int CL = 32 + KW - 1;
    constexpr int CLP = CL + 2;        // bank-conflict pad
    constexpr int NT = KH * KW;

    __shared__ float xs[2][CH][R][CLP];
    __shared__ float wsm[2][CH][NT][OC];

    const int tid = threadIdx.x;
    const int tx = tid & 31;           // output col j
    const int ty = tid >> 5;           // 0..7; out-ch = o0 + ty + 8*k
    const int o0 = blockIdx.x * OC;
    const int i0 = blockIdx.y * RT;
    const int b = blockIdx.z;

    float acc[RT][4];
#pragma unroll
    for (int r = 0; r < RT; ++r)
#pragma unroll
        for (int k = 0; k < 4; ++k) acc[r][k] = 0.f;

    const size_t xbase = ((size_t)b * FCH) << 10;

    for (int cb = 0; cb < FCH / CH; ++cb) {
        __syncthreads();
        // stage input tile, computing the concat_elu pair from one read
        for (int e = tid; e < CH * R * CL; e += 256) {
            int c = e / (R * CL);
            int rr = (e / CL) % R;
            int col = e % CL;
            int gi = i0 - PT + rr;
            int gj = col - PL;
            float v = 0.f;
            if (gi >= 0 && gi < 32 && gj >= 0 && gj < 32)
                v = x[xbase + (((size_t)(cb * CH + c)) << 10) + (gi << 5) + gj];
            float e0, e1;
            if (v > 0.f) { e0 = v; e1 = expm1f(-v); }
            else         { e0 = expm1f(v); e1 = -v; }
            xs[0][c][rr][col] = e0;
            xs[1][c][rr][col] = e1;
        }
        // stage weights: conv channel = s*160 + cb*8 + c
        for (int e = tid; e < 2 * CH * NT * OC; e += 256) {
            int o = e & 31;
            int rem = e >> 5;
            int tap = rem % NT;
            int c = (rem / NT) & 7;
            int s = rem / (NT * CH);
            wsm[s][c][tap][o] =
                w[((size_t)(o0 + o) * 320 + (size_t)s * FCH + cb * CH + c) * NT + tap];
        }
        __syncthreads();

#pragma unroll
        for (int s = 0; s < 2; ++s)
#pragma unroll
            for (int c = 0; c < CH; ++c)
#pragma unroll
                for (int kh = 0; kh < KH; ++kh)
#pragma unroll
                    for (int kw = 0; kw < KW; ++kw) {
                        const int tap = kh * KW + kw;
                        float wv[4], xv[4];
#pragma unroll
                        for (int k = 0; k < 4; ++k) wv[k] = wsm[s][c][tap][ty + 8 * k];
#pragma unroll
                        for (int r = 0; r < RT; ++r) xv[r] = xs[s][c][r + kh][tx + kw];
#pragma unroll
                        for (int r = 0; r < RT; ++r)
#pragma unroll
                            for (int k = 0; k < 4; ++k) acc[r][k] += wv[k] * xv[r];
                    }
    }

#pragma unroll
    for (int r = 0; r < RT; ++r) {
        int i = i0 + r;
#pragma unroll
        for (int k = 0; k < 4; ++k) {
            int o = o0 + ty + 8 * k;
            size_t idx = (((size_t)b * Cout + o) << 10) + (i << 5) + tx;
            float v = acc[r][k] + bias[o];
            if (ACC) v += y[idx];
            y[idx] = v;
        }
    }
}

// ---------------------------------------------------------------------------
// Gating epilogue: xio += c2[:160] * sigmoid(c2[160:])
// ---------------------------------------------------------------------------
__global__ __launch_bounds__(256) void gate_k(
    float* __restrict__ xio, const float* __restrict__ c2)
{
    int idx = blockIdx.x * 256 + threadIdx.x;
    if (idx >= BZ * FCH * 1024) return;
    int b = idx / (FCH * 1024);
    int rem = idx % (FCH * 1024);  // o*1024 + ij
    size_t cbase = (size_t)b * 320 * 1024 + rem;
    float g1 = c2[cbase];
    float g2 = c2[cbase + FCH * 1024];
    xio[idx] += g1 / (1.f + expf(-g2));
}

// ---------------------------------------------------------------------------
// Final nin: params = elu(ul) @ W^T + b    (plain elu, 160 -> 100)
// One block per (b, row). Stage elu(ul) row in LDS.
// ---------------------------------------------------------------------------
__global__ __launch_bounds__(256) void nin_out_k(
    const float* __restrict__ ul, const float* __restrict__ w,
    const float* __restrict__ bias, float* __restrict__ out)
{
    int bi = blockIdx.x;
    int b = bi >> 5, i = bi & 31;
    __shared__ float xe[FCH][33];
    for (int e = threadIdx.x; e < FCH * 32; e += 256) {
        int c = e >> 5, j = e & 31;
        float v = ul[(((size_t)b * FCH + c) << 10) + (i << 5) + j];
        xe[c][j] = v > 0.f ? v : expm1f(v);
    }
    __syncthreads();
    for (int e = threadIdx.x; e < PCH * 32; e += 256) {
        int o = e >> 5, j = e & 31;
        float acc = bias[o];
        const float* wp = w + o * FCH;
#pragma unroll 8
        for (int c = 0; c < FCH; ++c) acc += wp[c] * xe[c][j];
        out[(((size_t)b * PCH + o) << 10) + (i << 5) + j] = acc;
    }
}

// ---------------------------------------------------------------------------
// Discretized mixture of logistics loss, fused per-pixel + block reduction.
// Output = sum over pixels of logsumexp_n(log_probs)  (= -dmll)
// ---------------------------------------------------------------------------
__device__ __forceinline__ float softplus_f(float v) {
    return fmaxf(v, 0.f) + log1pf(expf(-fabsf(v)));
}
__device__ __forceinline__ float sigmoid_f(float v) {
    return 1.f / (1.f + expf(-v));
}
__device__ __forceinline__ float lpterm(float x, float m, float ls) {
    float inv = expf(-ls);
    float cen = x - m;
    float plus = inv * (cen + 0.00392156862745098f);
    float minv = inv * (cen - 0.00392156862745098f);
    float cdf_delta = sigmoid_f(plus) - sigmoid_f(minv);
    float log_cdf_plus = plus - softplus_f(plus);
    float log_om = -softplus_f(minv);
    float mid = inv * cen;
    float log_pdf_mid = mid - ls - 2.f * softplus_f(mid);
    float inner = (cdf_delta > 1e-5f) ? logf(fmaxf(cdf_delta, 1e-12f))
                                      : (log_pdf_mid - 4.848116389675623f); // log(127.5)
    return (x < -0.999f) ? log_cdf_plus : ((x > 0.999f) ? log_om : inner);
}

__global__ __launch_bounds__(256) void dmll_k(
    const float* __restrict__ smp, const float* __restrict__ params,
    float* __restrict__ partials)
{
    int idx = blockIdx.x * 256 + threadIdx.x;  // pixel index, 32768 total
    int b = idx >> 10;
    int ij = idx & 1023;
    const float* P = params + ((size_t)b * PCH << 10) + ij;

    float x0 = smp[(((size_t)b * 3 + 0) << 10) + ij] * 2.f - 1.f;
    float x1 = smp[(((size_t)b * 3 + 1) << 10) + ij] * 2.f - 1.f;
    float x2 = smp[(((size_t)b * 3 + 2) << 10) + ij] * 2.f - 1.f;

    float logit[NMIX];
    float mx = -1e30f;
#pragma unroll
    for (int n = 0; n < NMIX; ++n) { logit[n] = P[(size_t)n << 10]; mx = fmaxf(mx, logit[n]); }
    float se = 0.f;
#pragma unroll
    for (int n = 0; n < NMIX; ++n) se += expf(logit[n] - mx);
    float lse_logit = mx + logf(se);

    float lp[NMIX];
    float lpmax = -1e30f;
#pragma unroll
    for (int n = 0; n < NMIX; ++n) {
        float mean0 = P[(size_t)(10 + 0 * 30 + n) << 10];
        float mean1 = P[(size_t)(10 + 1 * 30 + n) << 10];
        float mean2 = P[(size_t)(10 + 2 * 30 + n) << 10];
        float ls0 = fmaxf(P[(size_t)(10 + 0 * 30 + 10 + n) << 10], -7.f);
        float ls1 = fmaxf(P[(size_t)(10 + 1 * 30 + 10 + n) << 10], -7.f);
        float ls2 = fmaxf(P[(size_t)(10 + 2 * 30 + 10 + n) << 10], -7.f);
        float c0 = tanhf(P[(size_t)(10 + 0 * 30 + 20 + n) << 10]);
        float c1 = tanhf(P[(size_t)(10 + 1 * 30 + 20 + n) << 10]);
        float c2 = tanhf(P[(size_t)(10 + 2 * 30 + 20 + n) << 10]);
        float m0 = mean0;
        float m1 = mean1 + c0 * x0;
        float m2 = mean2 + c1 * x0 + c2 * x1;
        float s3 = lpterm(x0, m0, ls0) + lpterm(x1, m1, ls1) + lpterm(x2, m2, ls2);
        lp[n] = s3 + logit[n] - lse_logit;
        lpmax = fmaxf(lpmax, lp[n]);
    }
    float se2 = 0.f;
#pragma unroll
    for (int n = 0; n < NMIX; ++n) se2 += expf(lp[n] - lpmax);
    float v = lpmax + logf(se2);

    // block reduce (4 waves)
#pragma unroll
    for (int off = 32; off > 0; off >>= 1) v += __shfl_down(v, off);
    __shared__ float red[4];
    int tid = threadIdx.x;
    if ((tid & 63) == 0) red[tid >> 6] = v;
    __syncthreads();
    if (tid == 0) partials[blockIdx.x] = red[0] + red[1] + red[2] + red[3];
}

__global__ void dmll_final_k(const float* __restrict__ partials, float* __restrict__ out)
{
    float v = partials[threadIdx.x];  // 128 threads
#pragma unroll
    for (int off = 32; off > 0; off >>= 1) v += __shfl_down(v, off);
    __shared__ float red[2];
    if ((threadIdx.x & 63) == 0) red[threadIdx.x >> 6] = v;
    __syncthreads();
    if (threadIdx.x == 0) out[0] = red[0] + red[1];
}

// ---------------------------------------------------------------------------
extern "C" void kernel_launch(void* const* d_in, const int* in_sizes, int n_in,
                              void* d_out, int out_size, void* d_ws, size_t ws_size,
                              hipStream_t stream)
{
    const float* samples  = (const float*)d_in[0];
    const float* w_u_init = (const float*)d_in[1];
    const float* b_u_init = (const float*)d_in[2];
    const float* w_ul_d   = (const float*)d_in[3];
    const float* b_ul_d   = (const float*)d_in[4];
    const float* w_ul_dr  = (const float*)d_in[5];
    const float* b_ul_dr  = (const float*)d_in[6];
    const float* u_c1_w   = (const float*)d_in[7];
    const float* u_c1_b   = (const float*)d_in[8];
    const float* u_c2_w   = (const float*)d_in[9];
    const float* u_c2_b   = (const float*)d_in[10];
    const float* ul_c1_w  = (const float*)d_in[11];
    const float* ul_c1_b  = (const float*)d_in[12];
    const float* ul_nin_w = (const float*)d_in[13];
    const float* ul_nin_b = (const float*)d_in[14];
    const float* ul_c2_w  = (const float*)d_in[15];
    const float* ul_c2_b  = (const float*)d_in[16];
    const float* nin_out_w = (const float*)d_in[17];
    const float* nin_out_b = (const float*)d_in[18];
    float* out = (float*)d_out;

    float* ws = (float*)d_ws;
    const size_t NU = (size_t)BZ * FCH * 1024;  // 5,242,880 floats
    float* u  = ws;
    float* ul = u + NU;
    float* c1 = ul + NU;
    float* c2 = c1 + NU;        // 2*NU floats (320 channels)
    float* params = c2;         // overlaps c2 region: only live after conv chain
    float* partials = c2 + 2 * NU;

    dim3 blk(256);
    const int total = BZ * FCH * 1024;
    const int gelem = (total + 255) / 256;

    init_u_k<<<gelem, blk, 0, stream>>>(samples, w_u_init, b_u_init, u);
    init_ul_k<<<gelem, blk, 0, stream>>>(samples, w_ul_d, b_ul_d, w_ul_dr, b_ul_dr, ul);

    for (int t = 0; t < 5; ++t) {
        // u stream: gated_resnet with ds_conv (2x3, pad top1 left1 right1)
        conv_ce_k<2, 3, 1, 1, false><<<dim3(5, 8, 32), blk, 0, stream>>>(
            u, u_c1_w + (size_t)t * 160 * 320 * 6, u_c1_b + t * 160, c1, 160);
        conv_ce_k<2, 3, 1, 1, false><<<dim3(10, 8, 32), blk, 0, stream>>>(
            c1, u_c2_w + (size_t)t * 320 * 320 * 6, u_c2_b + t * 320, c2, 320);
        gate_k<<<gelem, blk, 0, stream>>>(u, c2);
        // ul stream: gated_resnet with dr_conv (2x2, pad top1 left1) + nin(ce(u))
        conv_ce_k<2, 2, 1, 1, false><<<dim3(5, 8, 32), blk, 0, stream>>>(
            ul, ul_c1_w + (size_t)t * 160 * 320 * 4, ul_c1_b + t * 160, c1, 160);
        conv_ce_k<1, 1, 0, 0, true><<<dim3(5, 8, 32), blk, 0, stream>>>(
            u, ul_nin_w + (size_t)t * 160 * 320, ul_nin_b + t * 160, c1, 160);
        conv_ce_k<2, 2, 1, 1, false><<<dim3(10, 8, 32), blk, 0, stream>>>(
            c1, ul_c2_w + (size_t)t * 320 * 320 * 4, ul_c2_b + t * 320, c2, 320);
        gate_k<<<gelem, blk, 0, stream>>>(ul, c2);
    }

    nin_out_k<<<1024, blk, 0, stream>>>(ul, nin_out_w, nin_out_b, params);
    dmll_k<<<128, blk, 0, stream>>>(samples, params, partials);
    dmll_final_k<<<1, 128, 0, stream>>>(partials, out);
}

// Round 2
// 5424.143 us; speedup vs baseline: 2.2828x; 2.2828x over previous
//
#include <hip/hip_runtime.h>
#include <math.h>

#define BZ 32
#define FCH 160
#define NMIX 10
#define PCH 100

typedef __attribute__((ext_vector_type(8))) short bf16x8;
typedef __attribute__((ext_vector_type(4))) float f32x4;

__device__ __forceinline__ unsigned short f2bf(float f) {
    union { float f; unsigned u; } x; x.f = f;
    return (unsigned short)((x.u + 0x7FFFu + ((x.u >> 16) & 1u)) >> 16);
}

// ---------------------------------------------------------------------------
// Weight repack: w[NB][Cout][Cin][NT] fp32 -> wb[NB][CoutPad][NT][Cin] bf16,
// with optional concat-elu K interleave (k = 2c+s  ->  src channel s*Cin/2+c).
// Rows o >= Cout are zero (M padding for nin_out).
// ---------------------------------------------------------------------------
__global__ __launch_bounds__(256) void repack_k(
    const float* __restrict__ w, unsigned short* __restrict__ wb,
    int Cout, int CoutPad, int Cin, int NT, int ILV, int total)
{
    int idx = blockIdx.x * 256 + threadIdx.x;
    if (idx >= total) return;
    int k = idx % Cin;
    int tap = (idx / Cin) % NT;
    int o = (idx / (Cin * NT)) % CoutPad;
    int nb = idx / (Cin * NT * CoutPad);
    float v = 0.f;
    if (o < Cout) {
        int csrc = ILV ? ((k & 1) * (Cin >> 1) + (k >> 1)) : k;
        v = w[(((size_t)nb * Cout + o) * Cin + csrc) * NT + tap];
    }
    wb[idx] = f2bf(v);
}

// ---------------------------------------------------------------------------
// fp32 activation (B,160,32,32) -> CE bf16 (B,320,32,32), k=2c -> elu(x),
// k=2c+1 -> elu(-x).
// ---------------------------------------------------------------------------
__global__ __launch_bounds__(256) void ce2bf_k(
    const float* __restrict__ x, unsigned short* __restrict__ ce)
{
    int idx = blockIdx.x * 256 + threadIdx.x;
    if (idx >= BZ * FCH * 1024) return;
    int b = idx / (FCH * 1024);
    int rem = idx % (FCH * 1024);
    int c = rem >> 10, pix = rem & 1023;
    float v = x[idx];
    float e0 = v > 0.f ? v : expm1f(v);
    float e1 = v > 0.f ? expm1f(-v) : -v;
    ce[(((size_t)b * 320 + 2 * c) << 10) + pix] = f2bf(e0);
    ce[(((size_t)b * 320 + 2 * c + 1) << 10) + pix] = f2bf(e1);
}

// ---------------------------------------------------------------------------
// Init convs (tiny: 4 input channels) — keep scalar fp32.
// ---------------------------------------------------------------------------
__global__ __launch_bounds__(256) void init_u_k(
    const float* __restrict__ smp, const float* __restrict__ w,
    const float* __restrict__ bias, float* __restrict__ u)
{
    int idx = blockIdx.x * 256 + threadIdx.x;
    if (idx >= BZ * FCH * 1024) return;
    int b = idx / (FCH * 1024);
    int rem = idx % (FCH * 1024);
    int o = rem >> 10;
    int ij = rem & 1023;
    int i = ij >> 5, j = ij & 31;
    if (i == 0) { u[idx] = 0.f; return; }
    float acc = bias[o];
    const float* wb = w + o * 4 * 6;
    for (int kh = 0; kh < 2; ++kh) {
        int r = i - 2 + kh;
        if (r < 0) continue;
        for (int kw = 0; kw < 3; ++kw) {
            int cc = j - 1 + kw;
            if (cc < 0 || cc >= 32) continue;
            acc += wb[3 * 6 + kh * 3 + kw];
            for (int c = 0; c < 3; ++c) {
                float xv = smp[(((size_t)b * 3 + c) << 10) + (r << 5) + cc] * 2.f - 1.f;
                acc += wb[c * 6 + kh * 3 + kw] * xv;
            }
        }
    }
    u[idx] = acc;
}

__global__ __launch_bounds__(256) void init_ul_k(
    const float* __restrict__ smp,
    const float* __restrict__ wd, const float* __restrict__ bd,
    const float* __restrict__ wr, const float* __restrict__ br,
    float* __restrict__ ul)
{
    int idx = blockIdx.x * 256 + threadIdx.x;
    if (idx >= BZ * FCH * 1024) return;
    int b = idx / (FCH * 1024);
    int rem = idx % (FCH * 1024);
    int o = rem >> 10;
    int ij = rem & 1023;
    int i = ij >> 5, j = ij & 31;
    float acc = 0.f;
    if (i >= 1) {
        acc += bd[o];
        const float* wb = wd + o * 4 * 3;
        int r = i - 1;
        for (int kw = 0; kw < 3; ++kw) {
            int cc = j - 1 + kw;
            if (cc < 0 || cc >= 32) continue;
            acc += wb[3 * 3 + kw];
            for (int c = 0; c < 3; ++c)
                acc += wb[c * 3 + kw] * (smp[(((size_t)b * 3 + c) << 10) + (r << 5) + cc] * 2.f - 1.f);
        }
    }
    if (j >= 1) {
        acc += br[o];
        const float* wb = wr + o * 4 * 2;
        int cc = j - 1;
        for (int kh = 0; kh < 2; ++kh) {
            int r = i - 1 + kh;
            if (r < 0) continue;
            acc += wb[3 * 2 + kh];
            for (int c = 0; c < 3; ++c)
                acc += wb[c * 2 + kh] * (smp[(((size_t)b * 3 + c) << 10) + (r << 5) + cc] * 2.f - 1.f);
        }
    }
    ul[idx] = acc;
}

// ---------------------------------------------------------------------------
// MFMA implicit-GEMM conv.
// B tile: 8 rows x 32 cols of one image (blockIdx.y = b*4 + rowgroup).
// M tile: 32 out-ch (EPI!=GATE) or 64 = 32 g1-ch + matching 32 g2-ch (GATE).
// K loop: chunks of 32 over KIN (CE-interleaved channels), taps inside.
// Wave w owns rows {2w, 2w+1} (4 N-groups of 16 px) x all M tiles.
// ---------------------------------------------------------------------------
#define EPI_RAW 0
#define EPI_CE 1
#define EPI_GATE 2

template<int NRS, int NCS, int CWS, int KCP>
__device__ __forceinline__ void stageB(
    const unsigned short* __restrict__ ce, int bimg, int KCE, int kstr, int k0,
    int rowbase, int PT_, int PL_, unsigned short* bs, int tid)
{
    constexpr int RC = NRS * NCS;
    constexpr int TOT = RC * 32;
    for (int e = tid; e < TOT; e += 256) {
        int kk = e / RC;
        int rc = e - kk * RC;
        int r = rc / NCS;
        int c = rc - r * NCS;
        int grow = rowbase + r - PT_;
        int gcol = c - PL_;
        unsigned short v = 0;
        if (((unsigned)grow < 32u) && ((unsigned)gcol < 32u))
            v = ce[(((size_t)bimg * KCE + (size_t)(k0 + kk) * kstr) << 10) + (grow << 5) + gcol];
        bs[(r * CWS + c) * KCP + kk] = v;
    }
}

template<int MBLK, int KCP>
__device__ __forceinline__ void stageA(
    const unsigned short* __restrict__ wb, int NT_, int KIN_, int k0,
    int m0, bool gate, unsigned short* wsm, int tid)
{
    constexpr int MSH = (MBLK == 32) ? 5 : 6;
    int tot = NT_ * MBLK * 32;
    for (int e = tid; e < tot; e += 256) {
        int kk = e & 31;
        int mm = (e >> 5) & (MBLK - 1);
        int tap = e >> (5 + MSH);
        int o = gate ? (mm < 32 ? m0 + mm : 160 + m0 + mm - 32) : (m0 + mm);
        wsm[(tap * MBLK + mm) * KCP + kk] = wb[((size_t)o * NT_ + tap) * KIN_ + k0 + kk];
    }
}

template<int KH, int KW, int PT, int PL, bool DUAL, int EPI, int MBLK>
__global__ __launch_bounds__(256) void conv_mfma_k(
    const unsigned short* __restrict__ cein, int KCEin, int kstr, int KIN,
    const unsigned short* __restrict__ wb,
    const unsigned short* __restrict__ cein2, const unsigned short* __restrict__ wb2,
    const float* __restrict__ bias, const float* __restrict__ bias2,
    float* __restrict__ resid, float* __restrict__ yraw,
    unsigned short* __restrict__ ceout, int KCEout, int CoutR)
{
    constexpr int NT = KH * KW;
    constexpr int RW = 8 + KH - 1;
    constexpr int CW = 32 + KW - 1;
    constexpr int KCP = 40;  // K stride in halfwords: 80B -> 16B-aligned b128, ~2-way banks
    constexpr int MTILES = MBLK / 16;

    __shared__ __align__(16) unsigned short bs[RW * CW * KCP];
    __shared__ __align__(16) unsigned short wsm[NT * MBLK * KCP];

    const int tid = threadIdx.x;
    const int wv = tid >> 6;
    const int lane = tid & 63;
    const int l16 = lane & 15;
    const int quad = lane >> 4;
    const int m0 = blockIdx.x * 32;
    const int bimg = blockIdx.y >> 2;
    const int rowbase = (blockIdx.y & 3) * 8;

    f32x4 acc[MTILES][4];
#pragma unroll
    for (int mt = 0; mt < MTILES; ++mt)
#pragma unroll
        for (int ng = 0; ng < 4; ++ng)
#pragma unroll
            for (int r = 0; r < 4; ++r) acc[mt][ng][r] = 0.f;

    for (int k0 = 0; k0 < KIN; k0 += 32) {
        __syncthreads();
        stageB<RW, CW, CW, KCP>(cein, bimg, KCEin, kstr, k0, rowbase, PT, PL, bs, tid);
        stageA<MBLK, KCP>(wb, NT, KIN, k0, m0, EPI == EPI_GATE, wsm, tid);
        __syncthreads();
#pragma unroll
        for (int tap = 0; tap < NT; ++tap) {
            const int kh = tap / KW, kw = tap % KW;
            bf16x8 af[MTILES];
#pragma unroll
            for (int mt = 0; mt < MTILES; ++mt)
                af[mt] = *(const bf16x8*)&wsm[((tap * MBLK) + mt * 16 + l16) * KCP + quad * 8];
#pragma unroll
            for (int ng = 0; ng < 4; ++ng) {
                int rl = 2 * wv + (ng >> 1) + kh;
                int cc = (ng & 1) * 16 + l16 + kw;
                bf16x8 bfr = *(const bf16x8*)&bs[(rl * CW + cc) * KCP + quad * 8];
#pragma unroll
                for (int mt = 0; mt < MTILES; ++mt)
                    acc[mt][ng] = __builtin_amdgcn_mfma_f32_16x16x32_bf16(af[mt], bfr, acc[mt][ng], 0, 0, 0);
            }
        }
    }

    if (DUAL) {  // fused 1x1 nin over second CE input
        for (int k0 = 0; k0 < 320; k0 += 32) {
            __syncthreads();
            stageB<8, 32, CW, KCP>(cein2, bimg, 320, 1, k0, rowbase, 0, 0, bs, tid);
            stageA<MBLK, KCP>(wb2, 1, 320, k0, m0, false, wsm, tid);
            __syncthreads();
            bf16x8 af[MTILES];
#pragma unroll
            for (int mt = 0; mt < MTILES; ++mt)
                af[mt] = *(const bf16x8*)&wsm[(mt * 16 + l16) * KCP + quad * 8];
#pragma unroll
            for (int ng = 0; ng < 4; ++ng) {
                int rl = 2 * wv + (ng >> 1);
                int cc = (ng & 1) * 16 + l16;
                bf16x8 bfr = *(const bf16x8*)&bs[(rl * CW + cc) * KCP + quad * 8];
#pragma unroll
                for (int mt = 0; mt < MTILES; ++mt)
                    acc[mt][ng] = __builtin_amdgcn_mfma_f32_16x16x32_bf16(af[mt], bfr, acc[mt][ng], 0, 0, 0);
            }
        }
    }

    // epilogue
    constexpr int MOUT = (EPI == EPI_GATE) ? MTILES / 2 : MTILES;
#pragma unroll
    for (int mt = 0; mt < MOUT; ++mt) {
#pragma unroll
        for (int ng = 0; ng < 4; ++ng) {
            int i = rowbase + 2 * wv + (ng >> 1);
            int j = (ng & 1) * 16 + l16;
            int pix = (i << 5) + j;
#pragma unroll
            for (int r = 0; r < 4; ++r) {
                int o = m0 + mt * 16 + quad * 4 + r;
                if (EPI == EPI_RAW) {
                    if (o < CoutR)
                        yraw[(((size_t)bimg * CoutR + o) << 10) + pix] = acc[mt][ng][r] + bias[o];
                } else if (EPI == EPI_CE) {
                    float v = acc[mt][ng][r] + bias[o] + (DUAL ? bias2[o] : 0.f);
                    float e0 = v > 0.f ? v : expm1f(v);
                    float e1 = v > 0.f ? expm1f(-v) : -v;
                    ceout[(((size_t)bimg * KCEout + 2 * o) << 10) + pix] = f2bf(e0);
                    ceout[(((size_t)bimg * KCEout + 2 * o + 1) << 10) + pix] = f2bf(e1);
                } else {  // GATE
                    float g1 = acc[mt][ng][r] + bias[o];
                    float g2 = acc[mt + MTILES / 2][ng][r] + bias[o + 160];
                    size_t ridx = (((size_t)bimg * 160 + o) << 10) + pix;
                    float v = resid[ridx] + g1 / (1.f + expf(-g2));
                    resid[ridx] = v;
                    float e0 = v > 0.f ? v : expm1f(v);
                    float e1 = v > 0.f ? expm1f(-v) : -v;
                    ceout[(((size_t)bimg * KCEout + 2 * o) << 10) + pix] = f2bf(e0);
                    ceout[(((size_t)bimg * KCEout + 2 * o + 1) << 10) + pix] = f2bf(e1);
                }
            }
        }
    }
}

// ---------------------------------------------------------------------------
// DMLL (unchanged from round 1 — verified correct)
// ---------------------------------------------------------------------------
__device__ __forceinline__ float softplus_f(float v) {
    return fmaxf(v, 0.f) + log1pf(expf(-fabsf(v)));
}
__device__ __forceinline__ float sigmoid_f(float v) { return 1.f / (1.f + expf(-v)); }
__device__ __forceinline__ float lpterm(float x, float m, float ls) {
    float inv = expf(-ls);
    float cen = x - m;
    float plus = inv * (cen + 0.00392156862745098f);
    float minv = inv * (cen - 0.00392156862745098f);
    float cdf_delta = sigmoid_f(plus) - sigmoid_f(minv);
    float log_cdf_plus = plus - softplus_f(plus);
    float log_om = -softplus_f(minv);
    float mid = inv * cen;
    float log_pdf_mid = mid - ls - 2.f * softplus_f(mid);
    float inner = (cdf_delta > 1e-5f) ? logf(fmaxf(cdf_delta, 1e-12f))
                                      : (log_pdf_mid - 4.848116389675623f);
    return (x < -0.999f) ? log_cdf_plus : ((x > 0.999f) ? log_om : inner);
}

__global__ __launch_bounds__(256) void dmll_k(
    const float* __restrict__ smp, const float* __restrict__ params,
    float* __restrict__ partials)
{
    int idx = blockIdx.x * 256 + threadIdx.x;
    int b = idx >> 10;
    int ij = idx & 1023;
    const float* P = params + ((size_t)b * PCH << 10) + ij;

    float x0 = smp[(((size_t)b * 3 + 0) << 10) + ij] * 2.f - 1.f;
    float x1 = smp[(((size_t)b * 3 + 1) << 10) + ij] * 2.f - 1.f;
    float x2 = smp[(((size_t)b * 3 + 2) << 10) + ij] * 2.f - 1.f;

    float logit[NMIX];
    float mx = -1e30f;
#pragma unroll
    for (int n = 0; n < NMIX; ++n) { logit[n] = P[(size_t)n << 10]; mx = fmaxf(mx, logit[n]); }
    float se = 0.f;
#pragma unroll
    for (int n = 0; n < NMIX; ++n) se += expf(logit[n] - mx);
    float lse_logit = mx + logf(se);

    float lp[NMIX];
    float lpmax = -1e30f;
#pragma unroll
    for (int n = 0; n < NMIX; ++n) {
        float mean0 = P[(size_t)(10 + n) << 10];
        float mean1 = P[(size_t)(40 + n) << 10];
        float mean2 = P[(size_t)(70 + n) << 10];
        float ls0 = fmaxf(P[(size_t)(20 + n) << 10], -7.f);
        float ls1 = fmaxf(P[(size_t)(50 + n) << 10], -7.f);
        float ls2 = fmaxf(P[(size_t)(80 + n) << 10], -7.f);
        float c0 = tanhf(P[(size_t)(30 + n) << 10]);
        float c1 = tanhf(P[(size_t)(60 + n) << 10]);
        float c2 = tanhf(P[(size_t)(90 + n) << 10]);
        float m0 = mean0;
        float m1 = mean1 + c0 * x0;
        float m2 = mean2 + c1 * x0 + c2 * x1;
        float s3 = lpterm(x0, m0, ls0) + lpterm(x1, m1, ls1) + lpterm(x2, m2, ls2);
        lp[n] = s3 + logit[n] - lse_logit;
        lpmax = fmaxf(lpmax, lp[n]);
    }
    float se2 = 0.f;
#pragma unroll
    for (int n = 0; n < NMIX; ++n) se2 += expf(lp[n] - lpmax);
    float v = lpmax + logf(se2);

#pragma unroll
    for (int off = 32; off > 0; off >>= 1) v += __shfl_down(v, off);
    __shared__ float red[4];
    int tid = threadIdx.x;
    if ((tid & 63) == 0) red[tid >> 6] = v;
    __syncthreads();
    if (tid == 0) partials[blockIdx.x] = red[0] + red[1] + red[2] + red[3];
}

__global__ void dmll_final_k(const float* __restrict__ partials, float* __restrict__ out)
{
    float v = partials[threadIdx.x];
#pragma unroll
    for (int off = 32; off > 0; off >>= 1) v += __shfl_down(v, off);
    __shared__ float red[2];
    if ((threadIdx.x & 63) == 0) red[threadIdx.x >> 6] = v;
    __syncthreads();
    if (threadIdx.x == 0) out[0] = red[0] + red[1];
}

// ---------------------------------------------------------------------------
extern "C" void kernel_launch(void* const* d_in, const int* in_sizes, int n_in,
                              void* d_out, int out_size, void* d_ws, size_t ws_size,
                              hipStream_t stream)
{
    const float* samples   = (const float*)d_in[0];
    const float* w_u_init  = (const float*)d_in[1];
    const float* b_u_init  = (const float*)d_in[2];
    const float* w_ul_d    = (const float*)d_in[3];
    const float* b_ul_d    = (const float*)d_in[4];
    const float* w_ul_dr   = (const float*)d_in[5];
    const float* b_ul_dr   = (const float*)d_in[6];
    const float* u_c1_w    = (const float*)d_in[7];
    const float* u_c1_b    = (const float*)d_in[8];
    const float* u_c2_w    = (const float*)d_in[9];
    const float* u_c2_b    = (const float*)d_in[10];
    const float* ul_c1_w   = (const float*)d_in[11];
    const float* ul_c1_b   = (const float*)d_in[12];
    const float* ul_nin_w  = (const float*)d_in[13];
    const float* ul_nin_b  = (const float*)d_in[14];
    const float* ul_c2_w   = (const float*)d_in[15];
    const float* ul_c2_b   = (const float*)d_in[16];
    const float* nin_out_w = (const float*)d_in[17];
    const float* nin_out_b = (const float*)d_in[18];
    float* out = (float*)d_out;

    const size_t NU = (size_t)BZ * FCH * 1024;  // 5,242,880
    float* u  = (float*)d_ws;
    float* ul = u + NU;
    unsigned short* CEu  = (unsigned short*)(ul + NU);
    unsigned short* CEc1 = CEu + 2 * NU;
    unsigned short* CEul = CEc1 + 2 * NU;
    unsigned short* WBu1  = CEul + 2 * NU;
    unsigned short* WBu2  = WBu1 + (size_t)5 * 160 * 6 * 320;
    unsigned short* WBul1 = WBu2 + (size_t)5 * 320 * 6 * 320;
    unsigned short* WBnin = WBul1 + (size_t)5 * 160 * 4 * 320;
    unsigned short* WBul2 = WBnin + (size_t)5 * 160 * 1 * 320;
    unsigned short* WBnout = WBul2 + (size_t)5 * 320 * 4 * 320;
    float* partials = (float*)(WBnout + (size_t)128 * 160);
    float* params = (float*)CEc1;  // CEc1 dead by the time params is written

    dim3 blk(256);
    const int total = BZ * FCH * 1024;
    const int gelem = (total + 255) / 256;

    // weight repacks (cheap; must re-run every call since ws is re-poisoned)
    {
        int t;
        t = 5 * 160 * 6 * 320;
        repack_k<<<(t + 255) / 256, blk, 0, stream>>>(u_c1_w, WBu1, 160, 160, 320, 6, 1, t);
        t = 5 * 320 * 6 * 320;
        repack_k<<<(t + 255) / 256, blk, 0, stream>>>(u_c2_w, WBu2, 320, 320, 320, 6, 1, t);
        t = 5 * 160 * 4 * 320;
        repack_k<<<(t + 255) / 256, blk, 0, stream>>>(ul_c1_w, WBul1, 160, 160, 320, 4, 1, t);
        t = 5 * 160 * 1 * 320;
        repack_k<<<(t + 255) / 256, blk, 0, stream>>>(ul_nin_w, WBnin, 160, 160, 320, 1, 1, t);
        t = 5 * 320 * 4 * 320;
        repack_k<<<(t + 255) / 256, blk, 0, stream>>>(ul_c2_w, WBul2, 320, 320, 320, 4, 1, t);
        t = 128 * 1 * 160;
        repack_k<<<(t + 255) / 256, blk, 0, stream>>>(nin_out_w, WBnout, 100, 128, 160, 1, 0, t);
    }

    init_u_k<<<gelem, blk, 0, stream>>>(samples, w_u_init, b_u_init, u);
    init_ul_k<<<gelem, blk, 0, stream>>>(samples, w_ul_d, b_ul_d, w_ul_dr, b_ul_dr, ul);
    ce2bf_k<<<gelem, blk, 0, stream>>>(u, CEu);
    ce2bf_k<<<gelem, blk, 0, stream>>>(ul, CEul);

    for (int t = 0; t < 5; ++t) {
        // u_c1: ds 2x3, 320->160, epilogue writes ce(c1) into CEc1
        conv_mfma_k<2, 3, 1, 1, false, EPI_CE, 32><<<dim3(5, 128), blk, 0, stream>>>(
            CEu, 320, 1, 320, WBu1 + (size_t)t * 160 * 6 * 320,
            nullptr, nullptr, u_c1_b + t * 160, nullptr,
            nullptr, nullptr, CEc1, 320, 160);
        // u_c2: ds 2x3, 320->320, fused gate -> u fp32 + CEu
        conv_mfma_k<2, 3, 1, 1, false, EPI_GATE, 64><<<dim3(5, 128), blk, 0, stream>>>(
            CEc1, 320, 1, 320, WBu2 + (size_t)t * 320 * 6 * 320,
            nullptr, nullptr, u_c2_b + t * 320, nullptr,
            u, nullptr, CEu, 320, 160);
        // ul_c1 + fused nin(ce(u_new)): dr 2x2 + 1x1, -> ce into CEc1
        conv_mfma_k<2, 2, 1, 1, true, EPI_CE, 32><<<dim3(5, 128), blk, 0, stream>>>(
            CEul, 320, 1, 320, WBul1 + (size_t)t * 160 * 4 * 320,
            CEu, WBnin + (size_t)t * 160 * 320,
            ul_c1_b + t * 160, ul_nin_b + t * 160,
            nullptr, nullptr, CEc1, 320, 160);
        // ul_c2: dr 2x2, 320->320, fused gate -> ul fp32 + CEul
        conv_mfma_k<2, 2, 1, 1, false, EPI_GATE, 64><<<dim3(5, 128), blk, 0, stream>>>(
            CEc1, 320, 1, 320, WBul2 + (size_t)t * 320 * 4 * 320,
            nullptr, nullptr, ul_c2_b + t * 320, nullptr,
            ul, nullptr, CEul, 320, 160);
    }

    // nin_out: 1x1 over elu(ul) (even k of CEul via kstr=2), K=160, M padded to 128
    conv_mfma_k<1, 1, 0, 0, false, EPI_RAW, 32><<<dim3(4, 128), blk, 0, stream>>>(
        CEul, 320, 2, 160, WBnout,
        nullptr, nullptr, nin_out_b, nullptr,
        nullptr, params, nullptr, 0, 100);

    dmll_k<<<128, blk, 0, stream>>>(samples, params, partials);
    dmll_final_k<<<1, 128, 0, stream>>>(partials, out);
}

// Round 3
// 1879.760 us; speedup vs baseline: 6.5871x; 2.8856x over previous
//
#include <hip/hip_runtime.h>
#include <math.h>

#define BZ 32
#define FCH 160
#define NMIX 10
#define PCH 100

typedef __attribute__((ext_vector_type(8))) short bf16x8;
typedef __attribute__((ext_vector_type(8))) unsigned short u16x8;
typedef __attribute__((ext_vector_type(4))) unsigned short u16x4;
typedef __attribute__((ext_vector_type(4))) float f32x4;

__device__ __forceinline__ unsigned short f2bf(float f) {
    union { float f; unsigned u; } x; x.f = f;
    return (unsigned short)((x.u + 0x7FFFu + ((x.u >> 16) & 1u)) >> 16);
}
__device__ __forceinline__ void elupair(float v, float& e0, float& e1) {
    if (v > 0.f) { e0 = v; e1 = expm1f(-v); }
    else         { e0 = expm1f(v); e1 = -v; }
}

// ---------------------------------------------------------------------------
// Weight repack: w[NB][Cout][Cin][NT] fp32 -> wb[NB][CoutPad][NT][Cin] bf16,
// optional concat-elu K interleave (k=2c+s -> src channel s*Cin/2+c).
// ---------------------------------------------------------------------------
__global__ __launch_bounds__(256) void repack_k(
    const float* __restrict__ w, unsigned short* __restrict__ wb,
    int Cout, int CoutPad, int Cin, int NT, int ILV, int total)
{
    int idx = blockIdx.x * 256 + threadIdx.x;
    if (idx >= total) return;
    int k = idx % Cin;
    int tap = (idx / Cin) % NT;
    int o = (idx / (Cin * NT)) % CoutPad;
    int nb = idx / (Cin * NT * CoutPad);
    float v = 0.f;
    if (o < Cout) {
        int csrc = ILV ? ((k & 1) * (Cin >> 1) + (k >> 1)) : k;
        v = w[(((size_t)nb * Cout + o) * Cin + csrc) * NT + tap];
    }
    wb[idx] = f2bf(v);
}

// ---------------------------------------------------------------------------
// Init convs -> channel-last u/ul fp32 [b][pix][160] + CE bf16 [b][pix][320]
// ---------------------------------------------------------------------------
__global__ __launch_bounds__(256) void init_u_k(
    const float* __restrict__ smp, const float* __restrict__ w,
    const float* __restrict__ bias, float* __restrict__ u,
    unsigned short* __restrict__ ceu)
{
    int idx = blockIdx.x * 256 + threadIdx.x;
    if (idx >= BZ * 1024 * FCH) return;
    int o = idx % FCH;
    int pix = (idx / FCH) & 1023;
    int b = idx / (FCH * 1024);
    int i = pix >> 5, j = pix & 31;
    float acc = 0.f;
    if (i > 0) {
        acc = bias[o];
        const float* wb = w + o * 4 * 6;
        for (int kh = 0; kh < 2; ++kh) {
            int r = i - 2 + kh;
            if (r < 0) continue;
            for (int kw = 0; kw < 3; ++kw) {
                int cc = j - 1 + kw;
                if (cc < 0 || cc >= 32) continue;
                acc += wb[3 * 6 + kh * 3 + kw];
                for (int c = 0; c < 3; ++c)
                    acc += wb[c * 6 + kh * 3 + kw] *
                           (smp[(((size_t)b * 3 + c) << 10) + (r << 5) + cc] * 2.f - 1.f);
            }
        }
    }
    u[idx] = acc;
    float e0, e1; elupair(acc, e0, e1);
    size_t cb = (size_t)(((b << 10) | pix)) * 320 + 2 * o;
    ceu[cb] = f2bf(e0); ceu[cb + 1] = f2bf(e1);
}

__global__ __launch_bounds__(256) void init_ul_k(
    const float* __restrict__ smp,
    const float* __restrict__ wd, const float* __restrict__ bd,
    const float* __restrict__ wr, const float* __restrict__ br,
    float* __restrict__ ul, unsigned short* __restrict__ ceul)
{
    int idx = blockIdx.x * 256 + threadIdx.x;
    if (idx >= BZ * 1024 * FCH) return;
    int o = idx % FCH;
    int pix = (idx / FCH) & 1023;
    int b = idx / (FCH * 1024);
    int i = pix >> 5, j = pix & 31;
    float acc = 0.f;
    if (i >= 1) {
        acc += bd[o];
        const float* wb = wd + o * 4 * 3;
        int r = i - 1;
        for (int kw = 0; kw < 3; ++kw) {
            int cc = j - 1 + kw;
            if (cc < 0 || cc >= 32) continue;
            acc += wb[3 * 3 + kw];
            for (int c = 0; c < 3; ++c)
                acc += wb[c * 3 + kw] * (smp[(((size_t)b * 3 + c) << 10) + (r << 5) + cc] * 2.f - 1.f);
        }
    }
    if (j >= 1) {
        acc += br[o];
        const float* wb = wr + o * 4 * 2;
        int cc = j - 1;
        for (int kh = 0; kh < 2; ++kh) {
            int r = i - 1 + kh;
            if (r < 0) continue;
            acc += wb[3 * 2 + kh];
            for (int c = 0; c < 3; ++c)
                acc += wb[c * 2 + kh] * (smp[(((size_t)b * 3 + c) << 10) + (r << 5) + cc] * 2.f - 1.f);
        }
    }
    ul[idx] = acc;
    float e0, e1; elupair(acc, e0, e1);
    size_t cb = (size_t)(((b << 10) | pix)) * 320 + 2 * o;
    ceul[cb] = f2bf(e0); ceul[cb + 1] = f2bf(e1);
}

// ---------------------------------------------------------------------------
// MFMA implicit-GEMM conv, channel-last activations [b][pix][320].
// B tile: 8 rows x 32 cols; M tile: MBLK out-ch (GATE: 32 g1 + 32 g2).
// All staging is 16B-vectorized; LDS K-stride 40 halfwords (2-way banks, free).
// ---------------------------------------------------------------------------
template<int KH, int KW, int PT, int PL, bool DUAL, bool GATE, int MBLK>
__global__ __launch_bounds__(256) void conv_mfma_k(
    const unsigned short* __restrict__ cein,
    const unsigned short* __restrict__ wb,
    const unsigned short* __restrict__ cein2,
    const unsigned short* __restrict__ wb2,
    const float* __restrict__ bias, const float* __restrict__ bias2,
    float* __restrict__ resid,
    unsigned short* __restrict__ ceout)
{
    constexpr int NT = KH * KW;
    constexpr int RW = 8 + KH - 1;
    constexpr int CW = 32 + KW - 1;
    constexpr int KCP = 40;
    constexpr int MTILES = MBLK / 16;
    constexpr int MSH = (MBLK == 32) ? 5 : 6;

    __shared__ __align__(16) unsigned short bs[RW * CW * KCP];
    __shared__ __align__(16) unsigned short wsm[NT * MBLK * KCP];

    const int tid = threadIdx.x;
    const int wv = tid >> 6;
    const int lane = tid & 63;
    const int l16 = lane & 15;
    const int quad = lane >> 4;
    const int m0 = blockIdx.x * 32;
    const int bimg = blockIdx.y >> 2;
    const int rowbase = (blockIdx.y & 3) * 8;

    f32x4 acc[MTILES][4];
#pragma unroll
    for (int mt = 0; mt < MTILES; ++mt)
#pragma unroll
        for (int ng = 0; ng < 4; ++ng)
#pragma unroll
            for (int r = 0; r < 4; ++r) acc[mt][ng][r] = 0.f;

    for (int k0 = 0; k0 < 320; k0 += 32) {
        __syncthreads();
        // ---- stage B: vectorized bf16x8 per (pixel, k-segment)
        for (int e = tid; e < RW * CW * 4; e += 256) {
            int seg = e & 3;
            int p = e >> 2;
            int r = p / CW;
            int c = p - r * CW;
            int grow = rowbase + r - PT;
            int gcol = c - PL;
            bf16x8 v = {0, 0, 0, 0, 0, 0, 0, 0};
            if (((unsigned)grow < 32u) && ((unsigned)gcol < 32u))
                v = *(const bf16x8*)(cein +
                    (size_t)(((bimg << 10) | (grow << 5) | gcol)) * 320 + k0 + seg * 8);
            *(bf16x8*)(bs + p * KCP + seg * 8) = v;
        }
        // ---- stage A
        for (int e = tid; e < NT * MBLK * 4; e += 256) {
            int seg = e & 3;
            int mm = (e >> 2) & (MBLK - 1);
            int tap = e >> (2 + MSH);
            int o = GATE ? (mm < 32 ? m0 + mm : 128 + m0 + mm) : (m0 + mm);
            bf16x8 v = *(const bf16x8*)(wb + ((size_t)o * NT + tap) * 320 + k0 + seg * 8);
            *(bf16x8*)(wsm + (tap * MBLK + mm) * KCP + seg * 8) = v;
        }
        __syncthreads();
#pragma unroll
        for (int tap = 0; tap < NT; ++tap) {
            const int kh = tap / KW, kw = tap % KW;
            bf16x8 af[MTILES];
#pragma unroll
            for (int mt = 0; mt < MTILES; ++mt)
                af[mt] = *(const bf16x8*)&wsm[(tap * MBLK + mt * 16 + l16) * KCP + quad * 8];
#pragma unroll
            for (int ng = 0; ng < 4; ++ng) {
                int rl = 2 * wv + (ng >> 1) + kh;
                int cc = (ng & 1) * 16 + l16 + kw;
                bf16x8 bfr = *(const bf16x8*)&bs[(rl * CW + cc) * KCP + quad * 8];
#pragma unroll
                for (int mt = 0; mt < MTILES; ++mt)
                    acc[mt][ng] = __builtin_amdgcn_mfma_f32_16x16x32_bf16(af[mt], bfr, acc[mt][ng], 0, 0, 0);
            }
        }
    }

    if (DUAL) {  // fused 1x1 nin over second CE input (MBLK==32 path)
        for (int k0 = 0; k0 < 320; k0 += 32) {
            __syncthreads();
            for (int e = tid; e < 8 * 32 * 4; e += 256) {
                int seg = e & 3;
                int p = e >> 2;
                int r = p >> 5, c = p & 31;
                bf16x8 v = *(const bf16x8*)(cein2 +
                    (size_t)(((bimg << 10) | ((rowbase + r) << 5) | c)) * 320 + k0 + seg * 8);
                *(bf16x8*)(bs + (r * CW + c) * KCP + seg * 8) = v;
            }
            for (int e = tid; e < MBLK * 4; e += 256) {
                int seg = e & 3;
                int mm = e >> 2;
                bf16x8 v = *(const bf16x8*)(wb2 + (size_t)(m0 + mm) * 320 + k0 + seg * 8);
                *(bf16x8*)(wsm + mm * KCP + seg * 8) = v;
            }
            __syncthreads();
            bf16x8 af[MTILES];
#pragma unroll
            for (int mt = 0; mt < MTILES; ++mt)
                af[mt] = *(const bf16x8*)&wsm[(mt * 16 + l16) * KCP + quad * 8];
#pragma unroll
            for (int ng = 0; ng < 4; ++ng) {
                int rl = 2 * wv + (ng >> 1);
                int cc = (ng & 1) * 16 + l16;
                bf16x8 bfr = *(const bf16x8*)&bs[(rl * CW + cc) * KCP + quad * 8];
#pragma unroll
                for (int mt = 0; mt < MTILES; ++mt)
                    acc[mt][ng] = __builtin_amdgcn_mfma_f32_16x16x32_bf16(af[mt], bfr, acc[mt][ng], 0, 0, 0);
            }
        }
    }

    // ---- epilogue (vectorized channel-last stores)
    constexpr int MOUT = GATE ? MTILES / 2 : MTILES;
#pragma unroll
    for (int mt = 0; mt < MOUT; ++mt) {
        int ob = m0 + mt * 16 + quad * 4;
        f32x4 bv = *(const f32x4*)(bias + ob);
        f32x4 bv2;
        if (DUAL) bv2 = *(const f32x4*)(bias2 + ob);
        f32x4 bg;
        if (GATE) bg = *(const f32x4*)(bias + ob + 160);
#pragma unroll
        for (int ng = 0; ng < 4; ++ng) {
            int i = rowbase + 2 * wv + (ng >> 1);
            int j = (ng & 1) * 16 + l16;
            size_t pb = (size_t)((bimg << 10) | (i << 5) | j);
            if (!GATE) {
                u16x8 st;
#pragma unroll
                for (int r = 0; r < 4; ++r) {
                    float v = acc[mt][ng][r] + bv[r] + (DUAL ? bv2[r] : 0.f);
                    float e0, e1; elupair(v, e0, e1);
                    st[2 * r] = f2bf(e0); st[2 * r + 1] = f2bf(e1);
                }
                *(u16x8*)(ceout + pb * 320 + 2 * ob) = st;
            } else {
                f32x4 rv = *(const f32x4*)(resid + pb * 160 + ob);
                u16x8 st;
#pragma unroll
                for (int r = 0; r < 4; ++r) {
                    float g1 = acc[mt][ng][r] + bv[r];
                    float g2 = acc[mt + MTILES / 2][ng][r] + bg[r];
                    float v = rv[r] + g1 / (1.f + expf(-g2));
                    rv[r] = v;
                    float e0, e1; elupair(v, e0, e1);
                    st[2 * r] = f2bf(e0); st[2 * r + 1] = f2bf(e1);
                }
                *(f32x4*)(resid + pb * 160 + ob) = rv;
                *(u16x8*)(ceout + pb * 320 + 2 * ob) = st;
            }
        }
    }
}

// ---------------------------------------------------------------------------
// nin_out: params = elu(ul) @ W^T + b, K=160, M padded to 128.
// Stages directly from fp32 channel-last ul, elu+cvt in staging.
// Output layout [b][100][1024] (channel-major, matches dmll).
// ---------------------------------------------------------------------------
__global__ __launch_bounds__(256) void ninout_k(
    const float* __restrict__ ul, const unsigned short* __restrict__ wbn,
    const float* __restrict__ bias, float* __restrict__ params)
{
    constexpr int KCP = 40;
    __shared__ __align__(16) unsigned short bs[256 * KCP];
    __shared__ __align__(16) unsigned short wsm[32 * KCP];

    const int tid = threadIdx.x;
    const int wv = tid >> 6;
    const int lane = tid & 63;
    const int l16 = lane & 15;
    const int quad = lane >> 4;
    const int m0 = blockIdx.x * 32;
    const int bimg = blockIdx.y >> 2;
    const int rowbase = (blockIdx.y & 3) * 8;

    f32x4 acc[2][4];
#pragma unroll
    for (int mt = 0; mt < 2; ++mt)
#pragma unroll
        for (int ng = 0; ng < 4; ++ng)
#pragma unroll
            for (int r = 0; r < 4; ++r) acc[mt][ng][r] = 0.f;

    for (int k0 = 0; k0 < 160; k0 += 32) {
        __syncthreads();
        for (int e = tid; e < 256 * 8; e += 256) {
            int s = e & 7;
            int p = e >> 3;
            int pix = ((rowbase + (p >> 5)) << 5) | (p & 31);
            f32x4 xv = *(const f32x4*)(ul + (size_t)(((bimg << 10) | pix)) * 160 + k0 + s * 4);
            u16x4 st;
#pragma unroll
            for (int t = 0; t < 4; ++t) {
                float v = xv[t];
                st[t] = f2bf(v > 0.f ? v : expm1f(v));
            }
            *(u16x4*)(bs + p * KCP + s * 4) = st;
        }
        for (int e = tid; e < 32 * 4; e += 256) {
            int seg = e & 3;
            int mm = e >> 2;
            bf16x8 v = *(const bf16x8*)(wbn + (size_t)(m0 + mm) * 160 + k0 + seg * 8);
            *(bf16x8*)(wsm + mm * KCP + seg * 8) = v;
        }
        __syncthreads();
        bf16x8 af[2];
#pragma unroll
        for (int mt = 0; mt < 2; ++mt)
            af[mt] = *(const bf16x8*)&wsm[(mt * 16 + l16) * KCP + quad * 8];
#pragma unroll
        for (int ng = 0; ng < 4; ++ng) {
            int rl = 2 * wv + (ng >> 1);
            int cc = (ng & 1) * 16 + l16;
            bf16x8 bfr = *(const bf16x8*)&bs[(rl * 32 + cc) * KCP + quad * 8];
#pragma unroll
            for (int mt = 0; mt < 2; ++mt)
                acc[mt][ng] = __builtin_amdgcn_mfma_f32_16x16x32_bf16(af[mt], bfr, acc[mt][ng], 0, 0, 0);
        }
    }
#pragma unroll
    for (int mt = 0; mt < 2; ++mt)
#pragma unroll
        for (int ng = 0; ng < 4; ++ng) {
            int i = rowbase + 2 * wv + (ng >> 1);
            int j = (ng & 1) * 16 + l16;
            int pix = (i << 5) + j;
#pragma unroll
            for (int r = 0; r < 4; ++r) {
                int o = m0 + mt * 16 + quad * 4 + r;
                if (o < PCH)
                    params[(((size_t)bimg * PCH + o) << 10) + pix] = acc[mt][ng][r] + bias[o];
            }
        }
}

// ---------------------------------------------------------------------------
// DMLL (verified in rounds 1-2)
// ---------------------------------------------------------------------------
__device__ __forceinline__ float softplus_f(float v) {
    return fmaxf(v, 0.f) + log1pf(expf(-fabsf(v)));
}
__device__ __forceinline__ float sigmoid_f(float v) { return 1.f / (1.f + expf(-v)); }
__device__ __forceinline__ float lpterm(float x, float m, float ls) {
    float inv = expf(-ls);
    float cen = x - m;
    float plus = inv * (cen + 0.00392156862745098f);
    float minv = inv * (cen - 0.00392156862745098f);
    float cdf_delta = sigmoid_f(plus) - sigmoid_f(minv);
    float log_cdf_plus = plus - softplus_f(plus);
    float log_om = -softplus_f(minv);
    float mid = inv * cen;
    float log_pdf_mid = mid - ls - 2.f * softplus_f(mid);
    float inner = (cdf_delta > 1e-5f) ? logf(fmaxf(cdf_delta, 1e-12f))
                                      : (log_pdf_mid - 4.848116389675623f);
    return (x < -0.999f) ? log_cdf_plus : ((x > 0.999f) ? log_om : inner);
}

__global__ __launch_bounds__(256) void dmll_k(
    const float* __restrict__ smp, const float* __restrict__ params,
    float* __restrict__ partials)
{
    int idx = blockIdx.x * 256 + threadIdx.x;
    int b = idx >> 10;
    int ij = idx & 1023;
    const float* P = params + ((size_t)b * PCH << 10) + ij;

    float x0 = smp[(((size_t)b * 3 + 0) << 10) + ij] * 2.f - 1.f;
    float x1 = smp[(((size_t)b * 3 + 1) << 10) + ij] * 2.f - 1.f;
    float x2 = smp[(((size_t)b * 3 + 2) << 10) + ij] * 2.f - 1.f;

    float logit[NMIX];
    float mx = -1e30f;
#pragma unroll
    for (int n = 0; n < NMIX; ++n) { logit[n] = P[(size_t)n << 10]; mx = fmaxf(mx, logit[n]); }
    float se = 0.f;
#pragma unroll
    for (int n = 0; n < NMIX; ++n) se += expf(logit[n] - mx);
    float lse_logit = mx + logf(se);

    float lp[NMIX];
    float lpmax = -1e30f;
#pragma unroll
    for (int n = 0; n < NMIX; ++n) {
        float mean0 = P[(size_t)(10 + n) << 10];
        float mean1 = P[(size_t)(40 + n) << 10];
        float mean2 = P[(size_t)(70 + n) << 10];
        float ls0 = fmaxf(P[(size_t)(20 + n) << 10], -7.f);
        float ls1 = fmaxf(P[(size_t)(50 + n) << 10], -7.f);
        float ls2 = fmaxf(P[(size_t)(80 + n) << 10], -7.f);
        float c0 = tanhf(P[(size_t)(30 + n) << 10]);
        float c1 = tanhf(P[(size_t)(60 + n) << 10]);
        float c2 = tanhf(P[(size_t)(90 + n) << 10]);
        float m0 = mean0;
        float m1 = mean1 + c0 * x0;
        float m2 = mean2 + c1 * x0 + c2 * x1;
        float s3 = lpterm(x0, m0, ls0) + lpterm(x1, m1, ls1) + lpterm(x2, m2, ls2);
        lp[n] = s3 + logit[n] - lse_logit;
        lpmax = fmaxf(lpmax, lp[n]);
    }
    float se2 = 0.f;
#pragma unroll
    for (int n = 0; n < NMIX; ++n) se2 += expf(lp[n] - lpmax);
    float v = lpmax + logf(se2);

#pragma unroll
    for (int off = 32; off > 0; off >>= 1) v += __shfl_down(v, off);
    __shared__ float red[4];
    int tid = threadIdx.x;
    if ((tid & 63) == 0) red[tid >> 6] = v;
    __syncthreads();
    if (tid == 0) partials[blockIdx.x] = red[0] + red[1] + red[2] + red[3];
}

__global__ void dmll_final_k(const float* __restrict__ partials, float* __restrict__ out)
{
    float v = partials[threadIdx.x];
#pragma unroll
    for (int off = 32; off > 0; off >>= 1) v += __shfl_down(v, off);
    __shared__ float red[2];
    if ((threadIdx.x & 63) == 0) red[threadIdx.x >> 6] = v;
    __syncthreads();
    if (threadIdx.x == 0) out[0] = red[0] + red[1];
}

// ---------------------------------------------------------------------------
extern "C" void kernel_launch(void* const* d_in, const int* in_sizes, int n_in,
                              void* d_out, int out_size, void* d_ws, size_t ws_size,
                              hipStream_t stream)
{
    const float* samples   = (const float*)d_in[0];
    const float* w_u_init  = (const float*)d_in[1];
    const float* b_u_init  = (const float*)d_in[2];
    const float* w_ul_d    = (const float*)d_in[3];
    const float* b_ul_d    = (const float*)d_in[4];
    const float* w_ul_dr   = (const float*)d_in[5];
    const float* b_ul_dr   = (const float*)d_in[6];
    const float* u_c1_w    = (const float*)d_in[7];
    const float* u_c1_b    = (const float*)d_in[8];
    const float* u_c2_w    = (const float*)d_in[9];
    const float* u_c2_b    = (const float*)d_in[10];
    const float* ul_c1_w   = (const float*)d_in[11];
    const float* ul_c1_b   = (const float*)d_in[12];
    const float* ul_nin_w  = (const float*)d_in[13];
    const float* ul_nin_b  = (const float*)d_in[14];
    const float* ul_c2_w   = (const float*)d_in[15];
    const float* ul_c2_b   = (const float*)d_in[16];
    const float* nin_out_w = (const float*)d_in[17];
    const float* nin_out_b = (const float*)d_in[18];
    float* out = (float*)d_out;

    const size_t NU = (size_t)BZ * FCH * 1024;  // 5,242,880
    float* u  = (float*)d_ws;                    // [b][pix][160]
    float* ul = u + NU;
    unsigned short* CEu  = (unsigned short*)(ul + NU);   // [b][pix][320]
    unsigned short* CEc1 = CEu + 2 * NU;
    unsigned short* CEul = CEc1 + 2 * NU;
    unsigned short* WBu1  = CEul + 2 * NU;
    unsigned short* WBu2  = WBu1 + (size_t)5 * 160 * 6 * 320;
    unsigned short* WBul1 = WBu2 + (size_t)5 * 320 * 6 * 320;
    unsigned short* WBnin = WBul1 + (size_t)5 * 160 * 4 * 320;
    unsigned short* WBul2 = WBnin + (size_t)5 * 160 * 1 * 320;
    unsigned short* WBnout = WBul2 + (size_t)5 * 320 * 4 * 320;
    float* partials = (float*)(WBnout + (size_t)128 * 160);
    float* params = (float*)CEc1;  // CEc1 dead once ninout runs

    dim3 blk(256);
    const int total = BZ * FCH * 1024;
    const int gelem = (total + 255) / 256;

    {
        int t;
        t = 5 * 160 * 6 * 320;
        repack_k<<<(t + 255) / 256, blk, 0, stream>>>(u_c1_w, WBu1, 160, 160, 320, 6, 1, t);
        t = 5 * 320 * 6 * 320;
        repack_k<<<(t + 255) / 256, blk, 0, stream>>>(u_c2_w, WBu2, 320, 320, 320, 6, 1, t);
        t = 5 * 160 * 4 * 320;
        repack_k<<<(t + 255) / 256, blk, 0, stream>>>(ul_c1_w, WBul1, 160, 160, 320, 4, 1, t);
        t = 5 * 160 * 1 * 320;
        repack_k<<<(t + 255) / 256, blk, 0, stream>>>(ul_nin_w, WBnin, 160, 160, 320, 1, 1, t);
        t = 5 * 320 * 4 * 320;
        repack_k<<<(t + 255) / 256, blk, 0, stream>>>(ul_c2_w, WBul2, 320, 320, 320, 4, 1, t);
        t = 128 * 1 * 160;
        repack_k<<<(t + 255) / 256, blk, 0, stream>>>(nin_out_w, WBnout, 100, 128, 160, 1, 0, t);
    }

    init_u_k<<<gelem, blk, 0, stream>>>(samples, w_u_init, b_u_init, u, CEu);
    init_ul_k<<<gelem, blk, 0, stream>>>(samples, w_ul_d, b_ul_d, w_ul_dr, b_ul_dr, ul, CEul);

    for (int t = 0; t < 5; ++t) {
        conv_mfma_k<2, 3, 1, 1, false, false, 32><<<dim3(5, 128), blk, 0, stream>>>(
            CEu, WBu1 + (size_t)t * 160 * 6 * 320, nullptr, nullptr,
            u_c1_b + t * 160, nullptr, nullptr, CEc1);
        conv_mfma_k<2, 3, 1, 1, false, true, 64><<<dim3(5, 128), blk, 0, stream>>>(
            CEc1, WBu2 + (size_t)t * 320 * 6 * 320, nullptr, nullptr,
            u_c2_b + t * 320, nullptr, u, CEu);
        conv_mfma_k<2, 2, 1, 1, true, false, 32><<<dim3(5, 128), blk, 0, stream>>>(
            CEul, WBul1 + (size_t)t * 160 * 4 * 320, CEu, WBnin + (size_t)t * 160 * 320,
            ul_c1_b + t * 160, ul_nin_b + t * 160, nullptr, CEc1);
        conv_mfma_k<2, 2, 1, 1, false, true, 64><<<dim3(5, 128), blk, 0, stream>>>(
            CEc1, WBul2 + (size_t)t * 320 * 4 * 320, nullptr, nullptr,
            ul_c2_b + t * 320, nullptr, ul, CEul);
    }

    ninout_k<<<dim3(4, 128), blk, 0, stream>>>(ul, WBnout, nin_out_b, params);
    dmll_k<<<128, blk, 0, stream>>>(samples, params, partials);
    dmll_final_k<<<1, 128, 0, stream>>>(partials, out);
}